// Round 2
// baseline (11340.289 us; speedup 1.0000x reference)
//
#include <hip/hip_runtime.h>

// 2-layer LSTM, H=256, T=256, B=512, I=2, + linear head.
// 128 blocks x 512 threads, 4 batch elements per block, t-loop in-kernel.
// Gate-interleaved weight layout: row r (0..767), col 4*u+g holds the weight
// for gate g (i,f,g,o) of hidden unit u against input index r:
//   r in [0,256):   W_hh1[(g*256+u)][r]        (layer1, h1_prev)
//   r in [256,512): W_ih2[(g*256+u)][r-256]    (layer2, h1_new)
//   r in [512,768): W_hh2[(g*256+u)][r-512]    (layer2, h2_prev)
// Thread (u = tid&255, half = tid>>8) accumulates gates i,f,g,o for hidden
// unit u, batches {2*half, 2*half+1}, entirely in registers (vf4 acc per
// batch). h lives in LDS, double-buffered by t-parity -> 2 barriers/step.
// Weight stream is software-pipelined through two 8-row register buffers;
// the stream wraps across layers and t-steps so it never drains.

typedef float vf2 __attribute__((ext_vector_type(2)));
typedef float vf4 __attribute__((ext_vector_type(4)));

#define NT 512
#define NB 4
#define TSTEPS 256

#define WROWS 768
#define WX_OFF  (768 * 1024)
#define B1_OFF  (770 * 1024)
#define B2_OFF  (771 * 1024)

__global__ void prep_kernel(const float* __restrict__ W_ih1,
                            const float* __restrict__ W_hh1,
                            const float* __restrict__ b_ih1,
                            const float* __restrict__ b_hh1,
                            const float* __restrict__ W_ih2,
                            const float* __restrict__ W_hh2,
                            const float* __restrict__ b_ih2,
                            const float* __restrict__ b_hh2,
                            float* __restrict__ ws) {
    const int stride = gridDim.x * blockDim.x;
    const int idx = blockIdx.x * blockDim.x + threadIdx.x;
    for (int i = idx; i < WROWS * 1024; i += stride) {
        int r = i >> 10, c = i & 1023;
        int u = c >> 2, g = c & 3;
        int row = g * 256 + u;
        float v;
        if (r < 256)      v = W_hh1[row * 256 + r];
        else if (r < 512) v = W_ih2[row * 256 + (r - 256)];
        else              v = W_hh2[row * 256 + (r - 512)];
        ws[i] = v;
    }
    for (int i = idx; i < 2 * 1024; i += stride) {
        int xi = i >> 10, c = i & 1023;
        int u = c >> 2, g = c & 3;
        ws[WX_OFF + i] = W_ih1[(g * 256 + u) * 2 + xi];
    }
    for (int i = idx; i < 1024; i += stride) {
        int u = i >> 2, g = i & 3;
        int row = g * 256 + u;
        ws[B1_OFF + i] = b_ih1[row] + b_hh1[row];
        ws[B2_OFF + i] = b_ih2[row] + b_hh2[row];
    }
}

__device__ __forceinline__ float sig_(float x) {
    return 1.f / (1.f + __expf(-x));
}
__device__ __forceinline__ float tanh_(float x) {
    return 1.f - 2.f / (__expf(2.f * x) + 1.f);
}

// load 8 rows starting at (uniform) r into BUF; advance r with wrap at 768
#define LOADW(BUF) do {                                                  \
    const float* wp_ = wbase + r * 1024;                                 \
    _Pragma("unroll") for (int i_ = 0; i_ < 8; ++i_)                     \
        BUF[i_] = *(const vf4*)(wp_ + i_ * 1024);                        \
    r += 8; if (r == WROWS) r = 0;                                       \
} while (0)

// consume BUF (8 rows) against h[KK..KK+7] for the thread's two batches
#define USE8(BUF, P0, P1, KK) do {                                       \
    vf4 h0a_ = *(const vf4*)((P0) + (KK));                               \
    vf4 h0b_ = *(const vf4*)((P0) + (KK) + 4);                           \
    vf4 h1a_ = *(const vf4*)((P1) + (KK));                               \
    vf4 h1b_ = *(const vf4*)((P1) + (KK) + 4);                           \
    _Pragma("unroll") for (int i_ = 0; i_ < 4; ++i_) {                   \
        a0 += BUF[i_] * h0a_[i_]; a1 += BUF[i_] * h1a_[i_];              \
    }                                                                    \
    _Pragma("unroll") for (int i_ = 0; i_ < 4; ++i_) {                   \
        a0 += BUF[i_ + 4] * h0b_[i_]; a1 += BUF[i_ + 4] * h1b_[i_];      \
    }                                                                    \
} while (0)

__global__ __launch_bounds__(NT) void lstm_kernel(
    const float* __restrict__ x,      // (512, 256, 2)
    const float* __restrict__ ws,
    const float* __restrict__ W_lin,  // (2, 256)
    const float* __restrict__ b_lin,  // (2,)
    float* __restrict__ out)          // (512, 256, 2)
{
    const int tid = threadIdx.x;
    const int u = tid & 255;
    const int bA = (tid >> 8) << 1;   // 0 or 2
    const int b0 = blockIdx.x * NB;

    __shared__ float hb[2][NB][512];  // [parity][batch][k<256:h1, k>=256:h2]

    const float* __restrict__ wbase = ws + 4 * u;
    const vf4 wx0  = *(const vf4*)(ws + WX_OFF + 0 * 1024 + 4 * u);
    const vf4 wx1  = *(const vf4*)(ws + WX_OFF + 1 * 1024 + 4 * u);
    const vf4 bia1 = *(const vf4*)(ws + B1_OFF + 4 * u);
    const vf4 bia2 = *(const vf4*)(ws + B2_OFF + 4 * u);

    // output stage: wave wv -> (batch ob, output oo)
    const int lane = tid & 63, wv = tid >> 6;
    const int ob = wv >> 1, oo = wv & 1;
    const float wl0 = W_lin[oo * 256 + lane];
    const float wl1 = W_lin[oo * 256 + 64 + lane];
    const float wl2 = W_lin[oo * 256 + 128 + lane];
    const float wl3 = W_lin[oo * 256 + 192 + lane];
    const float blin = b_lin[oo];

    for (int i = tid; i < 2 * NB * 512; i += NT) ((float*)hb)[i] = 0.f;

    float c1_0 = 0.f, c1_1 = 0.f, c2_0 = 0.f, c2_1 = 0.f;

    const float* __restrict__ xr0 = x + (size_t)(b0 + bA) * (TSTEPS * 2);
    const float* __restrict__ xr1 = x + (size_t)(b0 + bA + 1) * (TSTEPS * 2);
    vf2 xa = *(const vf2*)(xr0);
    vf2 xb = *(const vf2*)(xr1);

    vf4 wA[8], wB[8];
    int r = 0;                 // uniform: next weight row to load
    LOADW(wA);                 // rows 0..7
    LOADW(wB);                 // rows 8..15
    __syncthreads();

    for (int t = 0; t < TSTEPS; ++t) {
        float*       __restrict__ hw = &hb[t & 1][0][0];
        const float* __restrict__ hr = &hb[(t + 1) & 1][0][0];
        const float* p0w = hw + bA * 512;
        const float* p1w = hw + (bA + 1) * 512;
        const float* p0r = hr + bA * 512;
        const float* p1r = hr + (bA + 1) * 512;

        vf4 a0 = bia1 + wx0 * xa.x + wx1 * xa.y;
        vf4 a1 = bia1 + wx0 * xb.x + wx1 * xb.y;

        // ---- layer 1: rows 0..255 vs h1_prev (hr) ----
        #pragma unroll 1
        for (int k = 0; k < 256; k += 16) {
            USE8(wA, p0r, p1r, k);     LOADW(wA);
            USE8(wB, p0r, p1r, k + 8); LOADW(wB);
        }
        c1_0 = sig_(a0.y) * c1_0 + sig_(a0.x) * tanh_(a0.z);
        c1_1 = sig_(a1.y) * c1_1 + sig_(a1.x) * tanh_(a1.z);
        hw[bA * 512 + u]       = sig_(a0.w) * tanh_(c1_0);
        hw[(bA + 1) * 512 + u] = sig_(a1.w) * tanh_(c1_1);
        __syncthreads();

        // ---- layer 2: rows 256..511 vs h1_new (hw), rows 512..767 vs h2_prev (hr) ----
        a0 = bia2; a1 = bia2;
        #pragma unroll 1
        for (int k = 0; k < 256; k += 16) {
            USE8(wA, p0w, p1w, k);     LOADW(wA);
            USE8(wB, p0w, p1w, k + 8); LOADW(wB);
        }
        #pragma unroll 1
        for (int k = 256; k < 512; k += 16) {
            USE8(wA, p0r, p1r, k);     LOADW(wA);
            USE8(wB, p0r, p1r, k + 8); LOADW(wB);
        }
        c2_0 = sig_(a0.y) * c2_0 + sig_(a0.x) * tanh_(a0.z);
        c2_1 = sig_(a1.y) * c2_1 + sig_(a1.x) * tanh_(a1.z);
        hw[bA * 512 + 256 + u]       = sig_(a0.w) * tanh_(c2_0);
        hw[(bA + 1) * 512 + 256 + u] = sig_(a1.w) * tanh_(c2_1);
        __syncthreads();

        // ---- output y = h2 @ W_lin.T + b_lin ----
        {
            const float* h2 = hw + ob * 512 + 256;
            float p = h2[lane] * wl0 + h2[64 + lane] * wl1
                    + h2[128 + lane] * wl2 + h2[192 + lane] * wl3;
            #pragma unroll
            for (int m = 32; m >= 1; m >>= 1) p += __shfl_xor(p, m, 64);
            if (lane == 0) out[(size_t)(b0 + ob) * (TSTEPS * 2) + t * 2 + oo] = p + blin;
        }

        // prefetch x for t+1 (wraps to 0 at the end; dummy, never used)
        int tn = (t + 1) & (TSTEPS - 1);
        xa = *(const vf2*)(xr0 + tn * 2);
        xb = *(const vf2*)(xr1 + tn * 2);
    }
}

extern "C" void kernel_launch(void* const* d_in, const int* in_sizes, int n_in,
                              void* d_out, int out_size, void* d_ws, size_t ws_size,
                              hipStream_t stream) {
    const float* x     = (const float*)d_in[0];
    const float* W_ih1 = (const float*)d_in[1];
    const float* W_hh1 = (const float*)d_in[2];
    const float* b_ih1 = (const float*)d_in[3];
    const float* b_hh1 = (const float*)d_in[4];
    const float* W_ih2 = (const float*)d_in[5];
    const float* W_hh2 = (const float*)d_in[6];
    const float* b_ih2 = (const float*)d_in[7];
    const float* b_hh2 = (const float*)d_in[8];
    const float* W_lin = (const float*)d_in[9];
    const float* b_lin = (const float*)d_in[10];
    float* ws = (float*)d_ws;
    float* out = (float*)d_out;

    prep_kernel<<<192, 256, 0, stream>>>(W_ih1, W_hh1, b_ih1, b_hh1,
                                         W_ih2, W_hh2, b_ih2, b_hh2, ws);
    lstm_kernel<<<512 / NB, NT, 0, stream>>>(x, ws, W_lin, b_lin, out);
}